// Round 7
// baseline (401.144 us; speedup 1.0000x reference)
//
#include <hip/hip_runtime.h>
#include <math.h>

// Problem constants (B,C,H,W fixed by the reference)
#define BB 4
#define CC 16
#define HH 256
#define WW 256
#define NN (HH*WW)        // 65536 pixels per batch
#define MM 256            // superpixels
#define CROW 20           // padded center row: c[0..17], [18]=||c||^2, [19]=pad
#define PROW 20           // pixel row: p[0..17], [18]=||p||^2, [19]=pad
#define PIX 32            // pixels per sub-tile
#define TSUB 4            // sub-tiles per block (128 px/block)
#define PIXPERBLK (PIX*TSUB)
#define CHUNKS (NN/PIXPERBLK)   // 512 chunks per batch

// ---------------------------------------------------------------------------
// Initial centers: 16x16 block means of features + analytic xy means + ||c||^2
// ---------------------------------------------------------------------------
__global__ void init_centers(const float* __restrict__ feat, float* __restrict__ cbuf)
{
    const int b    = blockIdx.x >> 8;
    const int m    = blockIdx.x & 255;
    const int lane = threadIdx.x;          // 0..63
    const int sy = m >> 4, sx = m & 15;

    float cvals[16];
#pragma unroll
    for (int d = 0; d < 16; ++d) {
        float v = 0.f;
#pragma unroll
        for (int k = 0; k < 4; ++k) {
            int q  = lane + (k << 6);            // 0..255 within 16x16 block
            int py = q >> 4, px = q & 15;
            int n  = (sy*16 + py)*WW + sx*16 + px;
            v += feat[((b*CC + d) << 16) + n];
        }
#pragma unroll
        for (int off = 32; off; off >>= 1) v += __shfl_down(v, off);
        cvals[d] = v * (1.f/256.f);
    }
    if (lane == 0) {
        float* row = cbuf + (b*MM + m)*CROW;
        float cn2 = 0.f;
#pragma unroll
        for (int d = 0; d < 16; ++d) { row[d] = cvals[d]; cn2 = fmaf(cvals[d], cvals[d], cn2); }
        float cx = (sx*16 + 7.5f) * (1.f/256.f);
        float cy = (sy*16 + 7.5f) * (1.f/256.f);
        row[16] = cx; row[17] = cy;
        cn2 = fmaf(cx, cx, cn2);
        cn2 = fmaf(cy, cy, cn2);
        row[18] = cn2;
        row[19] = 0.f;
    }
}

// ---------------------------------------------------------------------------
// Pre-transpose: pixel rows {p[0..17], ||p||^2, 0} into a CONTIGUOUS 20-float
// row array ptbuf[b][n][20] in d_ws (read-only for the rest of the pipeline).
// ---------------------------------------------------------------------------
__global__ void build_pt(const float* __restrict__ feat, float* __restrict__ ptbuf)
{
    const int b = blockIdx.x >> 8;
    const int n = ((blockIdx.x & 255) << 8) | threadIdx.x;
    float v[16];
#pragma unroll
    for (int d = 0; d < 16; ++d) v[d] = feat[((b*CC + d) << 16) + n];
    float x = (float)(n & 255) * (1.f/256.f);
    float y = (float)(n >> 8) * (1.f/256.f);
    float pn2 = 0.f;
#pragma unroll
    for (int d = 0; d < 16; ++d) pn2 = fmaf(v[d], v[d], pn2);
    pn2 = fmaf(x, x, pn2);
    pn2 = fmaf(y, y, pn2);
    float4* row = reinterpret_cast<float4*>(ptbuf + (size_t)(b*NN + n)*PROW);
    row[0] = make_float4(v[0],  v[1],  v[2],  v[3]);
    row[1] = make_float4(v[4],  v[5],  v[6],  v[7]);
    row[2] = make_float4(v[8],  v[9],  v[10], v[11]);
    row[3] = make_float4(v[12], v[13], v[14], v[15]);
    row[4] = make_float4(x, y, pn2, 0.f);
}

// ---------------------------------------------------------------------------
// Fused iteration kernel. thread = m; centers + e in registers.
// Non-final (A/B experiment): p rows read DIRECTLY from the read-only
//   __restrict__ ptbuf at statically wave-uniform addresses — eligible for
//   compiler s_load scalarization (SGPR broadcast, free across lanes).
// Final: p rows staged once into LDS (contiguous coalesced 10 KB copy) and
//   read as same-address broadcasts (proven ~105 us path).
// Non-final partials -> pp[b][chunk][m][20] (plain stores, no atomics).
// ---------------------------------------------------------------------------
template<bool FINAL>
__global__ __launch_bounds__(256, 4)
void ssn_iter(const float* __restrict__ ptbuf, const float* __restrict__ cbuf,
              float* __restrict__ wout)   // pp (non-final) or Q (final)
{
    __shared__ __align__(16) float pls[FINAL ? PIXPERBLK*PROW : 4];  // 10240 B (final)
    __shared__ float ssum_s[TSUB][4][PIX];
    __shared__ float w_s[TSUB][PIX];

    const int tid   = threadIdx.x;        // = m
    const int b     = blockIdx.x >> 9;
    const int chunk = blockIdx.x & (CHUNKS-1);
    const int n_base = chunk * PIXPERBLK;
    const int lane  = tid & 63;
    const int wv    = tid >> 6;

    if (FINAL) {
        // stage 128 rows x 80 B = 640 float4, fully coalesced
        const float4* src = reinterpret_cast<const float4*>(
            ptbuf + (size_t)(b*NN + n_base)*PROW);
#pragma unroll
        for (int k = 0; k < 3; ++k) {
            int f = tid + (k << 8);
            if (f < PIXPERBLK*PROW/4)
                reinterpret_cast<float4*>(pls)[f] = src[f];
        }
    }

    // center registers (per-lane vector loads, once per kernel)
    float c[18], cn2;
    {
        const float4* cv = reinterpret_cast<const float4*>(cbuf + (b*MM + tid)*CROW);
        float4 a0 = cv[0], a1 = cv[1], a2 = cv[2], a3 = cv[3], a4 = cv[4];
        c[0]=a0.x;  c[1]=a0.y;  c[2]=a0.z;  c[3]=a0.w;
        c[4]=a1.x;  c[5]=a1.y;  c[6]=a1.z;  c[7]=a1.w;
        c[8]=a2.x;  c[9]=a2.y;  c[10]=a2.z; c[11]=a2.w;
        c[12]=a3.x; c[13]=a3.y; c[14]=a3.z; c[15]=a3.w;
        c[16]=a4.x; c[17]=a4.y; cn2=a4.z;
    }

    float acc[19];
    if (!FINAL) {
#pragma unroll
        for (int d = 0; d < 19; ++d) acc[d] = 0.f;
    }

    const int l5  = lane & 31;
    const int pxo = ((l5&1)<<4) | ((l5&2)<<2) | (l5&4) | ((l5&8)>>2) | ((l5&16)>>4);

    if (FINAL) __syncthreads();   // pls ready

    for (int t = 0; t < TSUB; ++t) {
        // ---- phase 1: e[px] = exp(-dist(px, m)) into registers ----
        float e[PIX];
#pragma unroll
        for (int px = 0; px < PIX; ++px) {
            const float4* pv = FINAL
                ? reinterpret_cast<const float4*>(&pls[(t*PIX + px)*PROW])
                : reinterpret_cast<const float4*>(ptbuf + (size_t)(b*NN + n_base + t*PIX + px)*PROW);
            float4 q0 = pv[0], q1 = pv[1], q2 = pv[2], q3 = pv[3], q4 = pv[4];
            float dA, dB;
            dA = q0.x*c[0];             dB = q0.y*c[1];
            dA = fmaf(q0.z, c[2],  dA); dB = fmaf(q0.w, c[3],  dB);
            dA = fmaf(q1.x, c[4],  dA); dB = fmaf(q1.y, c[5],  dB);
            dA = fmaf(q1.z, c[6],  dA); dB = fmaf(q1.w, c[7],  dB);
            dA = fmaf(q2.x, c[8],  dA); dB = fmaf(q2.y, c[9],  dB);
            dA = fmaf(q2.z, c[10], dA); dB = fmaf(q2.w, c[11], dB);
            dA = fmaf(q3.x, c[12], dA); dB = fmaf(q3.y, c[13], dB);
            dA = fmaf(q3.z, c[14], dA); dB = fmaf(q3.w, c[15], dB);
            dA = fmaf(q4.x, c[16], dA); dB = fmaf(q4.y, c[17], dB);
            float d2   = fmaf(-2.f, dA + dB, q4.z + cn2);   // q4.z = ||p||^2
            float dist = __builtin_amdgcn_sqrtf(fmaxf(d2, 1e-12f));
            e[px] = __expf(-dist);
        }

        // ---- cross-thread sum over m: register reduce-scatter + butterfly ----
        float s[16];
        {
            const bool hi = (lane & 1);
#pragma unroll
            for (int k = 0; k < 16; ++k) {
                float a = e[k], bq = e[k+16];
                float recv = __shfl_xor(hi ? a : bq, 1);
                s[k] = (hi ? bq : a) + recv;
            }
        }
#define RS_ROUND(MASK, H) { const bool hi = (lane & (MASK)); \
        _Pragma("unroll") \
        for (int k = 0; k < (H); ++k) { \
            float a = s[k], bq = s[k+(H)]; \
            float recv = __shfl_xor(hi ? a : bq, (MASK)); \
            s[k] = (hi ? bq : a) + recv; } }
        RS_ROUND(2, 8)
        RS_ROUND(4, 4)
        RS_ROUND(8, 2)
        RS_ROUND(16, 1)
#undef RS_ROUND
        s[0] += __shfl_xor(s[0], 32);
        if (lane < 32) ssum_s[t][wv][pxo] = s[0];
        __syncthreads();
        if (tid < 32) {
            float tot = ssum_s[t][0][tid] + ssum_s[t][1][tid]
                      + ssum_s[t][2][tid] + ssum_s[t][3][tid];
            w_s[t][tid] = 1.0f / tot;
        }
        __syncthreads();

        // ---- phase 2 ----
        if (FINAL) {
            float* qb = wout + ((size_t)(b*NN + n_base + t*PIX) << 8) + tid;
#pragma unroll
            for (int px = 0; px < PIX; ++px)
                qb[(size_t)px << 8] = e[px] * w_s[t][px];
        } else {
#pragma unroll
            for (int px = 0; px < PIX; ++px) {
                const float4* pv = reinterpret_cast<const float4*>(
                    ptbuf + (size_t)(b*NN + n_base + t*PIX + px)*PROW);
                float4 q0 = pv[0], q1 = pv[1], q2 = pv[2], q3 = pv[3], q4 = pv[4];
                float ew = e[px] * w_s[t][px];
                acc[0]  = fmaf(ew, q0.x, acc[0]);   acc[1]  = fmaf(ew, q0.y, acc[1]);
                acc[2]  = fmaf(ew, q0.z, acc[2]);   acc[3]  = fmaf(ew, q0.w, acc[3]);
                acc[4]  = fmaf(ew, q1.x, acc[4]);   acc[5]  = fmaf(ew, q1.y, acc[5]);
                acc[6]  = fmaf(ew, q1.z, acc[6]);   acc[7]  = fmaf(ew, q1.w, acc[7]);
                acc[8]  = fmaf(ew, q2.x, acc[8]);   acc[9]  = fmaf(ew, q2.y, acc[9]);
                acc[10] = fmaf(ew, q2.z, acc[10]);  acc[11] = fmaf(ew, q2.w, acc[11]);
                acc[12] = fmaf(ew, q3.x, acc[12]);  acc[13] = fmaf(ew, q3.y, acc[13]);
                acc[14] = fmaf(ew, q3.z, acc[14]);  acc[15] = fmaf(ew, q3.w, acc[15]);
                acc[16] = fmaf(ew, q4.x, acc[16]);  acc[17] = fmaf(ew, q4.y, acc[17]);
                acc[18] += ew;
            }
        }
    }

    if (!FINAL) {
        float* dst = wout + ((size_t)(b*CHUNKS + chunk)*MM + tid)*PROW;
        float4* dv = reinterpret_cast<float4*>(dst);
        dv[0] = make_float4(acc[0],  acc[1],  acc[2],  acc[3]);
        dv[1] = make_float4(acc[4],  acc[5],  acc[6],  acc[7]);
        dv[2] = make_float4(acc[8],  acc[9],  acc[10], acc[11]);
        dv[3] = make_float4(acc[12], acc[13], acc[14], acc[15]);
        dv[4] = make_float4(acc[16], acc[17], acc[18], 0.f);
    }
}

// ---------------------------------------------------------------------------
// Sum the 512 per-chunk partials for each (b,m); produce new centers row
// (c, ||c||^2) and optionally centers_feat. block=(b,m), thread=chunk low 8b.
// Partials are hot in L2/L3 (just written) — scattered reads are cheap.
// ---------------------------------------------------------------------------
__global__ __launch_bounds__(256)
void reduce_finalize(const float* __restrict__ pp, float* __restrict__ cbuf,
                     float* __restrict__ cfout, int write_cf)
{
    const int b   = blockIdx.x >> 8;
    const int m   = blockIdx.x & 255;
    const int tid = threadIdx.x;
    const int lane = tid & 63, wv = tid >> 6;

    const float4* r0 = reinterpret_cast<const float4*>(
        pp + ((size_t)(b*CHUNKS + tid)*MM + m)*PROW);
    const float4* r1 = reinterpret_cast<const float4*>(
        pp + ((size_t)(b*CHUNKS + tid + 256)*MM + m)*PROW);
    float a[19];
    {
        float4 u0=r0[0], u1=r0[1], u2=r0[2], u3=r0[3], u4=r0[4];
        float4 w0=r1[0], w1=r1[1], w2=r1[2], w3=r1[3], w4=r1[4];
        a[0]=u0.x+w0.x;  a[1]=u0.y+w0.y;  a[2]=u0.z+w0.z;  a[3]=u0.w+w0.w;
        a[4]=u1.x+w1.x;  a[5]=u1.y+w1.y;  a[6]=u1.z+w1.z;  a[7]=u1.w+w1.w;
        a[8]=u2.x+w2.x;  a[9]=u2.y+w2.y;  a[10]=u2.z+w2.z; a[11]=u2.w+w2.w;
        a[12]=u3.x+w3.x; a[13]=u3.y+w3.y; a[14]=u3.z+w3.z; a[15]=u3.w+w3.w;
        a[16]=u4.x+w4.x; a[17]=u4.y+w4.y; a[18]=u4.z+w4.z;
    }
#pragma unroll
    for (int off = 32; off; off >>= 1) {
#pragma unroll
        for (int d = 0; d < 19; ++d) a[d] += __shfl_down(a[d], off);
    }

    __shared__ float red[4][20];
    if (lane == 0) {
#pragma unroll
        for (int d = 0; d < 19; ++d) red[wv][d] = a[d];
    }
    __syncthreads();
    if (tid == 0) {
        float s[19];
#pragma unroll
        for (int d = 0; d < 19; ++d)
            s[d] = red[0][d] + red[1][d] + red[2][d] + red[3][d];
        float den = s[18] + 1e-6f;
        float* row = cbuf + (b*MM + m)*CROW;
        float cn2 = 0.f;
#pragma unroll
        for (int d = 0; d < 18; ++d) {
            float cv = s[d] / den;
            row[d] = cv;
            cn2 = fmaf(cv, cv, cn2);
            if (write_cf && d < 16) cfout[((b*CC + d) << 8) + m] = cv;
        }
        row[18] = cn2;
        row[19] = 0.f;
    }
}

// ---------------------------------------------------------------------------
extern "C" void kernel_launch(void* const* d_in, const int* in_sizes, int n_in,
                              void* d_out, int out_size, void* d_ws, size_t ws_size,
                              hipStream_t stream)
{
    const float* feat = (const float*)d_in[0];
    float* dout = (float*)d_out;

    // d_ws layout: cbuf (80 KB) | ptbuf 21 MB | pp 42 MB
    float* cbuf  = (float*)d_ws;
    float* ptbuf = cbuf + 32768;
    float* pp    = ptbuf + (size_t)BB*NN*PROW;

    float* qout  = dout;                                // [B, N, M]
    float* cfout = dout + (size_t)BB*NN*MM;             // [B, C, M]

    build_pt<<<dim3(BB*256), dim3(256), 0, stream>>>(feat, ptbuf);
    init_centers<<<dim3(BB*MM), dim3(64), 0, stream>>>(feat, cbuf);

    for (int it = 0; it < 2; ++it) {
        ssn_iter<false><<<dim3(BB*CHUNKS), dim3(256), 0, stream>>>(ptbuf, cbuf, pp);
        reduce_finalize<<<dim3(BB*MM), dim3(256), 0, stream>>>(pp, cbuf, cfout, it == 1);
    }
    ssn_iter<true><<<dim3(BB*CHUNKS), dim3(256), 0, stream>>>(ptbuf, cbuf, qout);
}

// Round 8
// 335.106 us; speedup vs baseline: 1.1971x; 1.1971x over previous
//
#include <hip/hip_runtime.h>
#include <math.h>

// Problem constants (B,C,H,W fixed by the reference)
#define BB 4
#define CC 16
#define HH 256
#define WW 256
#define NN (HH*WW)        // 65536 pixels per batch
#define MM 256            // superpixels
#define CROW 20           // padded center row: c[0..17], [18]=||c||^2, [19]=pad
#define PROW 20           // pixel row: p[0..17], [18]=||p||^2, [19]=1.0
#define PIX 32            // pixels per sub-tile
#define TSUB 4            // sub-tiles per block (128 px/block)
#define PIXPERBLK (PIX*TSUB)
#define CHUNKS (NN/PIXPERBLK)   // 512 chunks per batch

typedef float f32x2 __attribute__((ext_vector_type(2)));

__device__ __forceinline__ f32x2 mk2(float a, float b) { f32x2 r; r.x = a; r.y = b; return r; }
// Packed fp32 FMA: lowers to v_pk_fma_f32 (VOP3P) — 2 lanes of f32 per instr.
__device__ __forceinline__ f32x2 pk_fma(f32x2 a, f32x2 b, f32x2 c) {
    return __builtin_elementwise_fma(a, b, c);
}

// ---------------------------------------------------------------------------
// Initial centers: 16x16 block means of features + analytic xy means + ||c||^2
// ---------------------------------------------------------------------------
__global__ void init_centers(const float* __restrict__ feat, float* __restrict__ cbuf)
{
    const int b    = blockIdx.x >> 8;
    const int m    = blockIdx.x & 255;
    const int lane = threadIdx.x;          // 0..63
    const int sy = m >> 4, sx = m & 15;

    float cvals[16];
#pragma unroll
    for (int d = 0; d < 16; ++d) {
        float v = 0.f;
#pragma unroll
        for (int k = 0; k < 4; ++k) {
            int q  = lane + (k << 6);            // 0..255 within 16x16 block
            int py = q >> 4, px = q & 15;
            int n  = (sy*16 + py)*WW + sx*16 + px;
            v += feat[((b*CC + d) << 16) + n];
        }
#pragma unroll
        for (int off = 32; off; off >>= 1) v += __shfl_down(v, off);
        cvals[d] = v * (1.f/256.f);
    }
    if (lane == 0) {
        float* row = cbuf + (b*MM + m)*CROW;
        float cn2 = 0.f;
#pragma unroll
        for (int d = 0; d < 16; ++d) { row[d] = cvals[d]; cn2 = fmaf(cvals[d], cvals[d], cn2); }
        float cx = (sx*16 + 7.5f) * (1.f/256.f);
        float cy = (sy*16 + 7.5f) * (1.f/256.f);
        row[16] = cx; row[17] = cy;
        cn2 = fmaf(cx, cx, cn2);
        cn2 = fmaf(cy, cy, cn2);
        row[18] = cn2;
        row[19] = 0.f;
    }
}

// ---------------------------------------------------------------------------
// Pre-transpose: pixel rows {p[0..17], ||p||^2, 1.0} into contiguous
// ptbuf[b][n][20] in d_ws. Slot 19 = 1.0 so the packed phase-2 pair
// {||p||^2, 1} accumulates the softmax denominator for free.
// ---------------------------------------------------------------------------
__global__ void build_pt(const float* __restrict__ feat, float* __restrict__ ptbuf)
{
    const int b = blockIdx.x >> 8;
    const int n = ((blockIdx.x & 255) << 8) | threadIdx.x;
    float v[16];
#pragma unroll
    for (int d = 0; d < 16; ++d) v[d] = feat[((b*CC + d) << 16) + n];
    float x = (float)(n & 255) * (1.f/256.f);
    float y = (float)(n >> 8) * (1.f/256.f);
    float pn2 = 0.f;
#pragma unroll
    for (int d = 0; d < 16; ++d) pn2 = fmaf(v[d], v[d], pn2);
    pn2 = fmaf(x, x, pn2);
    pn2 = fmaf(y, y, pn2);
    float4* row = reinterpret_cast<float4*>(ptbuf + (size_t)(b*NN + n)*PROW);
    row[0] = make_float4(v[0],  v[1],  v[2],  v[3]);
    row[1] = make_float4(v[4],  v[5],  v[6],  v[7]);
    row[2] = make_float4(v[8],  v[9],  v[10], v[11]);
    row[3] = make_float4(v[12], v[13], v[14], v[15]);
    row[4] = make_float4(x, y, pn2, 1.0f);
}

// ---------------------------------------------------------------------------
// Fused iteration kernel. thread = m; centers + e in registers; all 128 p-rows
// staged once into LDS (contiguous coalesced copy) and read as same-address
// ds_read_b128 broadcasts. Inner math in packed v_pk_fma_f32 pairs.
// Non-final partials -> pp[b][chunk][m][20] (plain stores, no atomics).
// ---------------------------------------------------------------------------
template<bool FINAL>
__global__ __launch_bounds__(256, 4)
void ssn_iter(const float* __restrict__ ptbuf, const float* __restrict__ cbuf,
              float* __restrict__ wout)   // pp (non-final) or Q (final)
{
    __shared__ __align__(16) float pls[PIXPERBLK*PROW];   // 10240 B
    __shared__ float ssum_s[TSUB][4][PIX];
    __shared__ float w_s[TSUB][PIX];

    const int tid   = threadIdx.x;        // = m
    const int b     = blockIdx.x >> 9;
    const int chunk = blockIdx.x & (CHUNKS-1);
    const int n_base = chunk * PIXPERBLK;
    const int lane  = tid & 63;
    const int wv    = tid >> 6;

    // ---- stage 128 rows x 80 B = 640 float4, fully coalesced & contiguous ----
    {
        const float4* src = reinterpret_cast<const float4*>(
            ptbuf + (size_t)(b*NN + n_base)*PROW);
#pragma unroll
        for (int k = 0; k < 3; ++k) {
            int f = tid + (k << 8);
            if (f < PIXPERBLK*PROW/4)
                reinterpret_cast<float4*>(pls)[f] = src[f];
        }
    }

    // center registers as packed pairs
    f32x2 cp[9]; float cn2;
    {
        const float4* cv = reinterpret_cast<const float4*>(cbuf + (b*MM + tid)*CROW);
        float4 a0 = cv[0], a1 = cv[1], a2 = cv[2], a3 = cv[3], a4 = cv[4];
        cp[0]=mk2(a0.x,a0.y); cp[1]=mk2(a0.z,a0.w);
        cp[2]=mk2(a1.x,a1.y); cp[3]=mk2(a1.z,a1.w);
        cp[4]=mk2(a2.x,a2.y); cp[5]=mk2(a2.z,a2.w);
        cp[6]=mk2(a3.x,a3.y); cp[7]=mk2(a3.z,a3.w);
        cp[8]=mk2(a4.x,a4.y); cn2=a4.z;
    }

    f32x2 acc2[10];
    if (!FINAL) {
#pragma unroll
        for (int k = 0; k < 10; ++k) acc2[k] = mk2(0.f, 0.f);
    }

    const int l5  = lane & 31;
    const int pxo = ((l5&1)<<4) | ((l5&2)<<2) | (l5&4) | ((l5&8)>>2) | ((l5&16)>>4);

    __syncthreads();   // pls ready

    for (int t = 0; t < TSUB; ++t) {
        // ---- phase 1: e[px] = exp(-dist(px, m)), packed dot ----
        float e[PIX];
#pragma unroll
        for (int px = 0; px < PIX; ++px) {
            const float4* pv = reinterpret_cast<const float4*>(&pls[(t*PIX + px)*PROW]);
            float4 q0 = pv[0], q1 = pv[1], q2 = pv[2], q3 = pv[3], q4 = pv[4];
            f32x2 dv = mk2(0.f, 0.f);
            dv = pk_fma(mk2(q0.x,q0.y), cp[0], dv);
            dv = pk_fma(mk2(q0.z,q0.w), cp[1], dv);
            dv = pk_fma(mk2(q1.x,q1.y), cp[2], dv);
            dv = pk_fma(mk2(q1.z,q1.w), cp[3], dv);
            dv = pk_fma(mk2(q2.x,q2.y), cp[4], dv);
            dv = pk_fma(mk2(q2.z,q2.w), cp[5], dv);
            dv = pk_fma(mk2(q3.x,q3.y), cp[6], dv);
            dv = pk_fma(mk2(q3.z,q3.w), cp[7], dv);
            dv = pk_fma(mk2(q4.x,q4.y), cp[8], dv);
            float d2   = fmaf(-2.f, dv.x + dv.y, q4.z + cn2);   // q4.z = ||p||^2
            float dist = __builtin_amdgcn_sqrtf(fmaxf(d2, 1e-12f));
            e[px] = __expf(-dist);
        }

        // ---- cross-thread sum over m: register reduce-scatter + butterfly ----
        float s[16];
        {
            const bool hi = (lane & 1);
#pragma unroll
            for (int k = 0; k < 16; ++k) {
                float a = e[k], bq = e[k+16];
                float recv = __shfl_xor(hi ? a : bq, 1);
                s[k] = (hi ? bq : a) + recv;
            }
        }
#define RS_ROUND(MASK, H) { const bool hi = (lane & (MASK)); \
        _Pragma("unroll") \
        for (int k = 0; k < (H); ++k) { \
            float a = s[k], bq = s[k+(H)]; \
            float recv = __shfl_xor(hi ? a : bq, (MASK)); \
            s[k] = (hi ? bq : a) + recv; } }
        RS_ROUND(2, 8)
        RS_ROUND(4, 4)
        RS_ROUND(8, 2)
        RS_ROUND(16, 1)
#undef RS_ROUND
        s[0] += __shfl_xor(s[0], 32);
        if (lane < 32) ssum_s[t][wv][pxo] = s[0];
        __syncthreads();
        if (tid < 32) {
            float tot = ssum_s[t][0][tid] + ssum_s[t][1][tid]
                      + ssum_s[t][2][tid] + ssum_s[t][3][tid];
            w_s[t][tid] = 1.0f / tot;
        }
        __syncthreads();

        // ---- phase 2 ----
        if (FINAL) {
            float* qb = wout + ((size_t)(b*NN + n_base + t*PIX) << 8) + tid;
#pragma unroll
            for (int px = 0; px < PIX; ++px)
                qb[(size_t)px << 8] = e[px] * w_s[t][px];
        } else {
#pragma unroll
            for (int px = 0; px < PIX; ++px) {
                const float4* pv = reinterpret_cast<const float4*>(&pls[(t*PIX + px)*PROW]);
                float4 q0 = pv[0], q1 = pv[1], q2 = pv[2], q3 = pv[3], q4 = pv[4];
                float ew = e[px] * w_s[t][px];
                f32x2 ew2 = mk2(ew, ew);
                acc2[0] = pk_fma(ew2, mk2(q0.x,q0.y), acc2[0]);
                acc2[1] = pk_fma(ew2, mk2(q0.z,q0.w), acc2[1]);
                acc2[2] = pk_fma(ew2, mk2(q1.x,q1.y), acc2[2]);
                acc2[3] = pk_fma(ew2, mk2(q1.z,q1.w), acc2[3]);
                acc2[4] = pk_fma(ew2, mk2(q2.x,q2.y), acc2[4]);
                acc2[5] = pk_fma(ew2, mk2(q2.z,q2.w), acc2[5]);
                acc2[6] = pk_fma(ew2, mk2(q3.x,q3.y), acc2[6]);
                acc2[7] = pk_fma(ew2, mk2(q3.z,q3.w), acc2[7]);
                acc2[8] = pk_fma(ew2, mk2(q4.x,q4.y), acc2[8]);
                acc2[9] = pk_fma(ew2, mk2(q4.z,q4.w), acc2[9]);  // {Sum ew*pn2, Sum ew}
            }
        }
    }

    if (!FINAL) {
        float* dst = wout + ((size_t)(b*CHUNKS + chunk)*MM + tid)*PROW;
        float4* dv4 = reinterpret_cast<float4*>(dst);
        dv4[0] = make_float4(acc2[0].x, acc2[0].y, acc2[1].x, acc2[1].y);
        dv4[1] = make_float4(acc2[2].x, acc2[2].y, acc2[3].x, acc2[3].y);
        dv4[2] = make_float4(acc2[4].x, acc2[4].y, acc2[5].x, acc2[5].y);
        dv4[3] = make_float4(acc2[6].x, acc2[6].y, acc2[7].x, acc2[7].y);
        dv4[4] = make_float4(acc2[8].x, acc2[8].y, acc2[9].y, 0.f);   // [18]=den
    }
}

// ---------------------------------------------------------------------------
// Sum the 512 per-chunk partials for each (b,m); produce new centers row
// (c, ||c||^2) and optionally centers_feat. block=(b,m), thread=chunk low 8b.
// ---------------------------------------------------------------------------
__global__ __launch_bounds__(256)
void reduce_finalize(const float* __restrict__ pp, float* __restrict__ cbuf,
                     float* __restrict__ cfout, int write_cf)
{
    const int b   = blockIdx.x >> 8;
    const int m   = blockIdx.x & 255;
    const int tid = threadIdx.x;
    const int lane = tid & 63, wv = tid >> 6;

    const float4* r0 = reinterpret_cast<const float4*>(
        pp + ((size_t)(b*CHUNKS + tid)*MM + m)*PROW);
    const float4* r1 = reinterpret_cast<const float4*>(
        pp + ((size_t)(b*CHUNKS + tid + 256)*MM + m)*PROW);
    float a[19];
    {
        float4 u0=r0[0], u1=r0[1], u2=r0[2], u3=r0[3], u4=r0[4];
        float4 w0=r1[0], w1=r1[1], w2=r1[2], w3=r1[3], w4=r1[4];
        a[0]=u0.x+w0.x;  a[1]=u0.y+w0.y;  a[2]=u0.z+w0.z;  a[3]=u0.w+w0.w;
        a[4]=u1.x+w1.x;  a[5]=u1.y+w1.y;  a[6]=u1.z+w1.z;  a[7]=u1.w+w1.w;
        a[8]=u2.x+w2.x;  a[9]=u2.y+w2.y;  a[10]=u2.z+w2.z; a[11]=u2.w+w2.w;
        a[12]=u3.x+w3.x; a[13]=u3.y+w3.y; a[14]=u3.z+w3.z; a[15]=u3.w+w3.w;
        a[16]=u4.x+w4.x; a[17]=u4.y+w4.y; a[18]=u4.z+w4.z;
    }
#pragma unroll
    for (int off = 32; off; off >>= 1) {
#pragma unroll
        for (int d = 0; d < 19; ++d) a[d] += __shfl_down(a[d], off);
    }

    __shared__ float red[4][20];
    if (lane == 0) {
#pragma unroll
        for (int d = 0; d < 19; ++d) red[wv][d] = a[d];
    }
    __syncthreads();
    if (tid == 0) {
        float s[19];
#pragma unroll
        for (int d = 0; d < 19; ++d)
            s[d] = red[0][d] + red[1][d] + red[2][d] + red[3][d];
        float den = s[18] + 1e-6f;
        float* row = cbuf + (b*MM + m)*CROW;
        float cn2 = 0.f;
#pragma unroll
        for (int d = 0; d < 18; ++d) {
            float cv = s[d] / den;
            row[d] = cv;
            cn2 = fmaf(cv, cv, cn2);
            if (write_cf && d < 16) cfout[((b*CC + d) << 8) + m] = cv;
        }
        row[18] = cn2;
        row[19] = 0.f;
    }
}

// ---------------------------------------------------------------------------
extern "C" void kernel_launch(void* const* d_in, const int* in_sizes, int n_in,
                              void* d_out, int out_size, void* d_ws, size_t ws_size,
                              hipStream_t stream)
{
    const float* feat = (const float*)d_in[0];
    float* dout = (float*)d_out;

    // d_ws layout: cbuf (128 KB) | ptbuf 21 MB | pp 42 MB
    float* cbuf  = (float*)d_ws;
    float* ptbuf = cbuf + 32768;
    float* pp    = ptbuf + (size_t)BB*NN*PROW;

    float* qout  = dout;                                // [B, N, M]
    float* cfout = dout + (size_t)BB*NN*MM;             // [B, C, M]

    build_pt<<<dim3(BB*256), dim3(256), 0, stream>>>(feat, ptbuf);
    init_centers<<<dim3(BB*MM), dim3(64), 0, stream>>>(feat, cbuf);

    for (int it = 0; it < 2; ++it) {
        ssn_iter<false><<<dim3(BB*CHUNKS), dim3(256), 0, stream>>>(ptbuf, cbuf, pp);
        reduce_finalize<<<dim3(BB*MM), dim3(256), 0, stream>>>(pp, cbuf, cfout, it == 1);
    }
    ssn_iter<true><<<dim3(BB*CHUNKS), dim3(256), 0, stream>>>(ptbuf, cbuf, qout);
}

// Round 9
// 273.723 us; speedup vs baseline: 1.4655x; 1.2243x over previous
//
#include <hip/hip_runtime.h>
#include <math.h>

// Problem constants (B,C,H,W fixed by the reference)
#define BB 4
#define CC 16
#define HH 256
#define WW 256
#define NN (HH*WW)        // 65536 pixels per batch
#define MM 256            // superpixels
#define CROW 20           // padded center row: c[0..17], [18]=||c||^2, [19]=pad
#define PROW 20           // pixel row: p[0..17], [18]=||p||^2, [19]=1.0
#define PIX 32            // pixels per sub-tile
#define TSUB 4            // sub-tiles per block (128 px/block)
#define PIXPERBLK (PIX*TSUB)
#define CHUNKS (NN/PIXPERBLK)   // 512 chunks per batch

typedef float f32x2 __attribute__((ext_vector_type(2)));

__device__ __forceinline__ f32x2 mk2(float a, float b) { f32x2 r; r.x = a; r.y = b; return r; }
// Packed fp32 FMA: lowers to v_pk_fma_f32 (VOP3P) — 2 lanes of f32 per instr.
__device__ __forceinline__ f32x2 pk_fma(f32x2 a, f32x2 b, f32x2 c) {
    return __builtin_elementwise_fma(a, b, c);
}

// ---------------------------------------------------------------------------
// Initial centers: 16x16 block means of features + analytic xy means + ||c||^2
// ---------------------------------------------------------------------------
__global__ void init_centers(const float* __restrict__ feat, float* __restrict__ cbuf)
{
    const int b    = blockIdx.x >> 8;
    const int m    = blockIdx.x & 255;
    const int lane = threadIdx.x;          // 0..63
    const int sy = m >> 4, sx = m & 15;

    float cvals[16];
#pragma unroll
    for (int d = 0; d < 16; ++d) {
        float v = 0.f;
#pragma unroll
        for (int k = 0; k < 4; ++k) {
            int q  = lane + (k << 6);            // 0..255 within 16x16 block
            int py = q >> 4, px = q & 15;
            int n  = (sy*16 + py)*WW + sx*16 + px;
            v += feat[((b*CC + d) << 16) + n];
        }
#pragma unroll
        for (int off = 32; off; off >>= 1) v += __shfl_down(v, off);
        cvals[d] = v * (1.f/256.f);
    }
    if (lane == 0) {
        float* row = cbuf + (b*MM + m)*CROW;
        float cn2 = 0.f;
#pragma unroll
        for (int d = 0; d < 16; ++d) { row[d] = cvals[d]; cn2 = fmaf(cvals[d], cvals[d], cn2); }
        float cx = (sx*16 + 7.5f) * (1.f/256.f);
        float cy = (sy*16 + 7.5f) * (1.f/256.f);
        row[16] = cx; row[17] = cy;
        cn2 = fmaf(cx, cx, cn2);
        cn2 = fmaf(cy, cy, cn2);
        row[18] = cn2;
        row[19] = 0.f;
    }
}

// ---------------------------------------------------------------------------
// Pre-transpose: pixel rows {p[0..17], ||p||^2, 1.0} into contiguous
// ptbuf[b][n][20] in d_ws. Slot 19 = 1.0 so the packed phase-2 pair
// {||p||^2, 1} accumulates the softmax denominator for free.
// ---------------------------------------------------------------------------
__global__ void build_pt(const float* __restrict__ feat, float* __restrict__ ptbuf)
{
    const int b = blockIdx.x >> 8;
    const int n = ((blockIdx.x & 255) << 8) | threadIdx.x;
    float v[16];
#pragma unroll
    for (int d = 0; d < 16; ++d) v[d] = feat[((b*CC + d) << 16) + n];
    float x = (float)(n & 255) * (1.f/256.f);
    float y = (float)(n >> 8) * (1.f/256.f);
    float pn2 = 0.f;
#pragma unroll
    for (int d = 0; d < 16; ++d) pn2 = fmaf(v[d], v[d], pn2);
    pn2 = fmaf(x, x, pn2);
    pn2 = fmaf(y, y, pn2);
    float4* row = reinterpret_cast<float4*>(ptbuf + (size_t)(b*NN + n)*PROW);
    row[0] = make_float4(v[0],  v[1],  v[2],  v[3]);
    row[1] = make_float4(v[4],  v[5],  v[6],  v[7]);
    row[2] = make_float4(v[8],  v[9],  v[10], v[11]);
    row[3] = make_float4(v[12], v[13], v[14], v[15]);
    row[4] = make_float4(x, y, pn2, 1.0f);
}

// ---------------------------------------------------------------------------
// Fused iteration kernel, KM=2: thread handles m0=tid&127 and m1=m0+128 over
// a 16-pixel half (pxhalf = tid>>7) — each LDS p-row read is amortized over
// 2 centers, halving broadcast traffic (the measured bottleneck).
// p-rows staged once into LDS, read as same-address ds_read_b128 broadcasts.
// Softmax denominator: 16-value register reduce-scatter per wave + LDS
// combine of the 4 waves. Non-final partials for (m0,m1) combined across
// pxhalf partners via LDS xfer, then stored to pp (plain stores, no atomics).
// ---------------------------------------------------------------------------
template<bool FINAL>
__global__ __launch_bounds__(256, 3)
void ssn_iter(const float* __restrict__ ptbuf, const float* __restrict__ cbuf,
              float* __restrict__ wout)   // pp (non-final) or Q (final)
{
    __shared__ __align__(16) float pls[PIXPERBLK*PROW];   // 10240 B
    __shared__ float ssum_s[TSUB][4][16];                 //  1024 B
    __shared__ float w_s[TSUB][PIX];                      //   512 B
    __shared__ float xfer[FINAL ? 4 : 128*41];            // 20992 B (non-final)

    const int tid    = threadIdx.x;
    const int b      = blockIdx.x >> 9;
    const int chunk  = blockIdx.x & (CHUNKS-1);
    const int n_base = chunk * PIXPERBLK;
    const int lane   = tid & 63;
    const int wv     = tid >> 6;
    const int mlo    = tid & 127;          // m0 = mlo, m1 = mlo + 128
    const int pxbase = (tid >> 7) << 4;    // 0 or 16

    // ---- stage 128 rows x 80 B = 640 float4, fully coalesced & contiguous ----
    {
        const float4* src = reinterpret_cast<const float4*>(
            ptbuf + (size_t)(b*NN + n_base)*PROW);
#pragma unroll
        for (int k = 0; k < 3; ++k) {
            int f = tid + (k << 8);
            if (f < PIXPERBLK*PROW/4)
                reinterpret_cast<float4*>(pls)[f] = src[f];
        }
    }

    // center registers for both m's, as packed pairs
    f32x2 cp0[9], cp1[9]; float cn20, cn21;
    {
        const float4* cv = reinterpret_cast<const float4*>(cbuf + (b*MM + mlo)*CROW);
        float4 a0 = cv[0], a1 = cv[1], a2 = cv[2], a3 = cv[3], a4 = cv[4];
        cp0[0]=mk2(a0.x,a0.y); cp0[1]=mk2(a0.z,a0.w);
        cp0[2]=mk2(a1.x,a1.y); cp0[3]=mk2(a1.z,a1.w);
        cp0[4]=mk2(a2.x,a2.y); cp0[5]=mk2(a2.z,a2.w);
        cp0[6]=mk2(a3.x,a3.y); cp0[7]=mk2(a3.z,a3.w);
        cp0[8]=mk2(a4.x,a4.y); cn20=a4.z;
    }
    {
        const float4* cv = reinterpret_cast<const float4*>(cbuf + (b*MM + mlo + 128)*CROW);
        float4 a0 = cv[0], a1 = cv[1], a2 = cv[2], a3 = cv[3], a4 = cv[4];
        cp1[0]=mk2(a0.x,a0.y); cp1[1]=mk2(a0.z,a0.w);
        cp1[2]=mk2(a1.x,a1.y); cp1[3]=mk2(a1.z,a1.w);
        cp1[4]=mk2(a2.x,a2.y); cp1[5]=mk2(a2.z,a2.w);
        cp1[6]=mk2(a3.x,a3.y); cp1[7]=mk2(a3.z,a3.w);
        cp1[8]=mk2(a4.x,a4.y); cn21=a4.z;
    }

    f32x2 acc0[10], acc1[10];
    if (!FINAL) {
#pragma unroll
        for (int k = 0; k < 10; ++k) { acc0[k] = mk2(0.f,0.f); acc1[k] = mk2(0.f,0.f); }
    }

    // lane -> owned px_local after the 4-round reduce-scatter (bitrev4)
    const int pxo4 = ((lane&1)<<3) | ((lane&2)<<1) | ((lane&4)>>1) | ((lane&8)>>3);

    __syncthreads();   // pls ready

    for (int t = 0; t < TSUB; ++t) {
        // ---- phase 1: e for 2 m's x 16 px; each p-row read serves 2 dots ----
        float e0[16], e1[16];
#pragma unroll
        for (int k = 0; k < 16; ++k) {
            const float4* pv = reinterpret_cast<const float4*>(
                &pls[(t*PIX + pxbase + k)*PROW]);
            float4 q0 = pv[0], q1 = pv[1], q2 = pv[2], q3 = pv[3], q4 = pv[4];
            f32x2 u0=mk2(q0.x,q0.y), u1=mk2(q0.z,q0.w), u2=mk2(q1.x,q1.y),
                  u3=mk2(q1.z,q1.w), u4=mk2(q2.x,q2.y), u5=mk2(q2.z,q2.w),
                  u6=mk2(q3.x,q3.y), u7=mk2(q3.z,q3.w), u8=mk2(q4.x,q4.y);
            f32x2 d0 = mk2(0.f,0.f), d1 = mk2(0.f,0.f);
            d0 = pk_fma(u0, cp0[0], d0);  d1 = pk_fma(u0, cp1[0], d1);
            d0 = pk_fma(u1, cp0[1], d0);  d1 = pk_fma(u1, cp1[1], d1);
            d0 = pk_fma(u2, cp0[2], d0);  d1 = pk_fma(u2, cp1[2], d1);
            d0 = pk_fma(u3, cp0[3], d0);  d1 = pk_fma(u3, cp1[3], d1);
            d0 = pk_fma(u4, cp0[4], d0);  d1 = pk_fma(u4, cp1[4], d1);
            d0 = pk_fma(u5, cp0[5], d0);  d1 = pk_fma(u5, cp1[5], d1);
            d0 = pk_fma(u6, cp0[6], d0);  d1 = pk_fma(u6, cp1[6], d1);
            d0 = pk_fma(u7, cp0[7], d0);  d1 = pk_fma(u7, cp1[7], d1);
            d0 = pk_fma(u8, cp0[8], d0);  d1 = pk_fma(u8, cp1[8], d1);
            float d20 = fmaf(-2.f, d0.x + d0.y, q4.z + cn20);
            float d21 = fmaf(-2.f, d1.x + d1.y, q4.z + cn21);
            e0[k] = __expf(-__builtin_amdgcn_sqrtf(fmaxf(d20, 1e-12f)));
            e1[k] = __expf(-__builtin_amdgcn_sqrtf(fmaxf(d21, 1e-12f)));
        }

        // ---- per-px sum over this wave's 128 m's: 16-value reduce-scatter ----
        float s[8];
        {
            const bool hi = (lane & 1);
#pragma unroll
            for (int k = 0; k < 8; ++k) {
                float a  = e0[k]   + e1[k];
                float bq = e0[k+8] + e1[k+8];
                float recv = __shfl_xor(hi ? a : bq, 1);
                s[k] = (hi ? bq : a) + recv;
            }
        }
#define RS_ROUND(MASK, H) { const bool hi = (lane & (MASK)); \
        _Pragma("unroll") \
        for (int k = 0; k < (H); ++k) { \
            float a = s[k], bq = s[k+(H)]; \
            float recv = __shfl_xor(hi ? a : bq, (MASK)); \
            s[k] = (hi ? bq : a) + recv; } }
        RS_ROUND(2, 4)
        RS_ROUND(4, 2)
        RS_ROUND(8, 1)
#undef RS_ROUND
        s[0] += __shfl_xor(s[0], 16);
        s[0] += __shfl_xor(s[0], 32);
        if (lane < 16) ssum_s[t][wv][pxo4] = s[0];
        __syncthreads();
        if (tid < 32) {
            int h = tid >> 4, p4 = tid & 15;   // px = tid; halves from wave pairs
            w_s[t][tid] = 1.0f / (ssum_s[t][2*h][p4] + ssum_s[t][2*h+1][p4]);
        }
        __syncthreads();

        // ---- phase 2 ----
        if (FINAL) {
#pragma unroll
            for (int k = 0; k < 16; ++k) {
                float w = w_s[t][pxbase + k];
                size_t rowoff = ((size_t)(b*NN + n_base + t*PIX + pxbase + k) << 8);
                wout[rowoff + mlo]       = e0[k] * w;
                wout[rowoff + mlo + 128] = e1[k] * w;
            }
        } else {
#pragma unroll
            for (int k = 0; k < 16; ++k) {
                const float4* pv = reinterpret_cast<const float4*>(
                    &pls[(t*PIX + pxbase + k)*PROW]);
                float4 q0 = pv[0], q1 = pv[1], q2 = pv[2], q3 = pv[3], q4 = pv[4];
                float w = w_s[t][pxbase + k];
                float w0 = e0[k]*w, w1 = e1[k]*w;
                f32x2 ew0 = mk2(w0, w0), ew1 = mk2(w1, w1);
                f32x2 u0=mk2(q0.x,q0.y), u1=mk2(q0.z,q0.w), u2=mk2(q1.x,q1.y),
                      u3=mk2(q1.z,q1.w), u4=mk2(q2.x,q2.y), u5=mk2(q2.z,q2.w),
                      u6=mk2(q3.x,q3.y), u7=mk2(q3.z,q3.w), u8=mk2(q4.x,q4.y),
                      u9=mk2(q4.z,q4.w);
                acc0[0] = pk_fma(ew0, u0, acc0[0]);  acc1[0] = pk_fma(ew1, u0, acc1[0]);
                acc0[1] = pk_fma(ew0, u1, acc0[1]);  acc1[1] = pk_fma(ew1, u1, acc1[1]);
                acc0[2] = pk_fma(ew0, u2, acc0[2]);  acc1[2] = pk_fma(ew1, u2, acc1[2]);
                acc0[3] = pk_fma(ew0, u3, acc0[3]);  acc1[3] = pk_fma(ew1, u3, acc1[3]);
                acc0[4] = pk_fma(ew0, u4, acc0[4]);  acc1[4] = pk_fma(ew1, u4, acc1[4]);
                acc0[5] = pk_fma(ew0, u5, acc0[5]);  acc1[5] = pk_fma(ew1, u5, acc1[5]);
                acc0[6] = pk_fma(ew0, u6, acc0[6]);  acc1[6] = pk_fma(ew1, u6, acc1[6]);
                acc0[7] = pk_fma(ew0, u7, acc0[7]);  acc1[7] = pk_fma(ew1, u7, acc1[7]);
                acc0[8] = pk_fma(ew0, u8, acc0[8]);  acc1[8] = pk_fma(ew1, u8, acc1[8]);
                acc0[9] = pk_fma(ew0, u9, acc0[9]);  acc1[9] = pk_fma(ew1, u9, acc1[9]);
            }
        }
    }

    if (!FINAL) {
        // combine px-half partials across partner threads (tid <-> tid^128),
        // then store 2 pp rows. Stride 41 (odd) -> conflict-free scalar slots.
        if (tid >= 128) {
            float* xb = &xfer[(tid - 128)*41];
#pragma unroll
            for (int j = 0; j < 10; ++j) { xb[2*j]    = acc0[j].x; xb[2*j+1]    = acc0[j].y; }
#pragma unroll
            for (int j = 0; j < 10; ++j) { xb[20+2*j] = acc1[j].x; xb[20+2*j+1] = acc1[j].y; }
        }
        __syncthreads();
        if (tid < 128) {
            const float* xb = &xfer[tid*41];
#pragma unroll
            for (int j = 0; j < 10; ++j) { acc0[j].x += xb[2*j];    acc0[j].y += xb[2*j+1]; }
#pragma unroll
            for (int j = 0; j < 10; ++j) { acc1[j].x += xb[20+2*j]; acc1[j].y += xb[20+2*j+1]; }

            float* dst0 = wout + ((size_t)(b*CHUNKS + chunk)*MM + mlo)*PROW;
            float4* v0 = reinterpret_cast<float4*>(dst0);
            v0[0] = make_float4(acc0[0].x, acc0[0].y, acc0[1].x, acc0[1].y);
            v0[1] = make_float4(acc0[2].x, acc0[2].y, acc0[3].x, acc0[3].y);
            v0[2] = make_float4(acc0[4].x, acc0[4].y, acc0[5].x, acc0[5].y);
            v0[3] = make_float4(acc0[6].x, acc0[6].y, acc0[7].x, acc0[7].y);
            v0[4] = make_float4(acc0[8].x, acc0[8].y, acc0[9].y, 0.f);   // [18]=den

            float* dst1 = wout + ((size_t)(b*CHUNKS + chunk)*MM + mlo + 128)*PROW;
            float4* v1 = reinterpret_cast<float4*>(dst1);
            v1[0] = make_float4(acc1[0].x, acc1[0].y, acc1[1].x, acc1[1].y);
            v1[1] = make_float4(acc1[2].x, acc1[2].y, acc1[3].x, acc1[3].y);
            v1[2] = make_float4(acc1[4].x, acc1[4].y, acc1[5].x, acc1[5].y);
            v1[3] = make_float4(acc1[6].x, acc1[6].y, acc1[7].x, acc1[7].y);
            v1[4] = make_float4(acc1[8].x, acc1[8].y, acc1[9].y, 0.f);
        }
    }
}

// ---------------------------------------------------------------------------
// Sum the 512 per-chunk partials for each (b,m); produce new centers row
// (c, ||c||^2) and optionally centers_feat. block=(b,m), thread=chunk low 8b.
// ---------------------------------------------------------------------------
__global__ __launch_bounds__(256)
void reduce_finalize(const float* __restrict__ pp, float* __restrict__ cbuf,
                     float* __restrict__ cfout, int write_cf)
{
    const int b   = blockIdx.x >> 8;
    const int m   = blockIdx.x & 255;
    const int tid = threadIdx.x;
    const int lane = tid & 63, wv = tid >> 6;

    const float4* r0 = reinterpret_cast<const float4*>(
        pp + ((size_t)(b*CHUNKS + tid)*MM + m)*PROW);
    const float4* r1 = reinterpret_cast<const float4*>(
        pp + ((size_t)(b*CHUNKS + tid + 256)*MM + m)*PROW);
    float a[19];
    {
        float4 u0=r0[0], u1=r0[1], u2=r0[2], u3=r0[3], u4=r0[4];
        float4 w0=r1[0], w1=r1[1], w2=r1[2], w3=r1[3], w4=r1[4];
        a[0]=u0.x+w0.x;  a[1]=u0.y+w0.y;  a[2]=u0.z+w0.z;  a[3]=u0.w+w0.w;
        a[4]=u1.x+w1.x;  a[5]=u1.y+w1.y;  a[6]=u1.z+w1.z;  a[7]=u1.w+w1.w;
        a[8]=u2.x+w2.x;  a[9]=u2.y+w2.y;  a[10]=u2.z+w2.z; a[11]=u2.w+w2.w;
        a[12]=u3.x+w3.x; a[13]=u3.y+w3.y; a[14]=u3.z+w3.z; a[15]=u3.w+w3.w;
        a[16]=u4.x+w4.x; a[17]=u4.y+w4.y; a[18]=u4.z+w4.z;
    }
#pragma unroll
    for (int off = 32; off; off >>= 1) {
#pragma unroll
        for (int d = 0; d < 19; ++d) a[d] += __shfl_down(a[d], off);
    }

    __shared__ float red[4][20];
    if (lane == 0) {
#pragma unroll
        for (int d = 0; d < 19; ++d) red[wv][d] = a[d];
    }
    __syncthreads();
    if (tid == 0) {
        float s[19];
#pragma unroll
        for (int d = 0; d < 19; ++d)
            s[d] = red[0][d] + red[1][d] + red[2][d] + red[3][d];
        float den = s[18] + 1e-6f;
        float* row = cbuf + (b*MM + m)*CROW;
        float cn2 = 0.f;
#pragma unroll
        for (int d = 0; d < 18; ++d) {
            float cv = s[d] / den;
            row[d] = cv;
            cn2 = fmaf(cv, cv, cn2);
            if (write_cf && d < 16) cfout[((b*CC + d) << 8) + m] = cv;
        }
        row[18] = cn2;
        row[19] = 0.f;
    }
}

// ---------------------------------------------------------------------------
extern "C" void kernel_launch(void* const* d_in, const int* in_sizes, int n_in,
                              void* d_out, int out_size, void* d_ws, size_t ws_size,
                              hipStream_t stream)
{
    const float* feat = (const float*)d_in[0];
    float* dout = (float*)d_out;

    // d_ws layout: cbuf (128 KB) | ptbuf 21 MB | pp 42 MB
    float* cbuf  = (float*)d_ws;
    float* ptbuf = cbuf + 32768;
    float* pp    = ptbuf + (size_t)BB*NN*PROW;

    float* qout  = dout;                                // [B, N, M]
    float* cfout = dout + (size_t)BB*NN*MM;             // [B, C, M]

    build_pt<<<dim3(BB*256), dim3(256), 0, stream>>>(feat, ptbuf);
    init_centers<<<dim3(BB*MM), dim3(64), 0, stream>>>(feat, cbuf);

    for (int it = 0; it < 2; ++it) {
        ssn_iter<false><<<dim3(BB*CHUNKS), dim3(256), 0, stream>>>(ptbuf, cbuf, pp);
        reduce_finalize<<<dim3(BB*MM), dim3(256), 0, stream>>>(pp, cbuf, cfout, it == 1);
    }
    ssn_iter<true><<<dim3(BB*CHUNKS), dim3(256), 0, stream>>>(ptbuf, cbuf, qout);
}